// Round 3
// baseline (330.493 us; speedup 1.0000x reference)
//
#include <hip/hip_runtime.h>

// Masked BCE: cost = sum(t==1 ? -log(p) : t==0 ? -log(1-p) : 0) / count(t<=1)
// Latency-bound streaming reduction -> deep MLP: 8x unrolled grid-stride,
// 16 independent dwordx4 loads in flight per wave.
// n = 8192*5000 = 40,960,000; n4 = 10,240,000 = (1000 blocks * 256 thr) * 8 * 5
// -> exactly 5 outer iterations per thread, no tail.

#define GRID_BLOCKS 1000
#define BLOCK 256
#define UNROLL 8

__global__ __launch_bounds__(BLOCK) void bce_reduce_kernel(
    const float* __restrict__ prob,
    const int* __restrict__ tgt,
    float* __restrict__ part_sum,        // [GRID_BLOCKS]
    unsigned int* __restrict__ part_cnt, // [GRID_BLOCKS]
    int n)                               // total elements (fits int32)
{
    const int tid    = blockIdx.x * BLOCK + threadIdx.x;
    const int stride = GRID_BLOCKS * BLOCK;
    const int n4     = n >> 2;

    float        lsum = 0.0f;
    unsigned int lcnt = 0u;

    const float4* __restrict__ p4 = (const float4*)prob;
    const int4*   __restrict__ t4 = (const int4*)tgt;

    #define ACC(P, T)                                   \
    {                                                   \
        float v = ((T) == 1) ? (P) : 1.0f - (P);        \
        bool  c = (unsigned)(T) <= 1u;                  \
        float l = -__logf(v);                           \
        lsum += c ? l : 0.0f;                           \
        lcnt += c ? 1u : 0u;                            \
    }
    #define ACC4(P, T) ACC((P).x,(T).x) ACC((P).y,(T).y) ACC((P).z,(T).z) ACC((P).w,(T).w)

    int i = tid;
    // main loop: UNROLL independent float4+int4 pairs -> 16 loads in flight
    for (; i + (UNROLL - 1) * stride < n4; i += UNROLL * stride) {
        float4 p[UNROLL];
        int4   t[UNROLL];
        #pragma unroll
        for (int j = 0; j < UNROLL; ++j) {
            p[j] = p4[i + j * stride];
            t[j] = t4[i + j * stride];
        }
        #pragma unroll
        for (int j = 0; j < UNROLL; ++j) {
            ACC4(p[j], t[j])
        }
    }
    // vector tail (not taken for the bench shape, kept for generality)
    for (; i < n4; i += stride) {
        float4 p = p4[i];
        int4   t = t4[i];
        ACC4(p, t)
    }
    // scalar tail (n % 4 != 0)
    for (int k = (n4 << 2) + tid; k < n; k += stride) {
        float p = prob[k];
        int   t = tgt[k];
        ACC(p, t)
    }

    // wave-64 reduction
    #pragma unroll
    for (int off = 32; off > 0; off >>= 1) {
        lsum += __shfl_down(lsum, off, 64);
        lcnt += __shfl_down(lcnt, off, 64);
    }

    // cross-wave via LDS (4 waves)
    __shared__ float        s_sum[4];
    __shared__ unsigned int s_cnt[4];
    const int lane = threadIdx.x & 63;
    const int wave = threadIdx.x >> 6;
    if (lane == 0) { s_sum[wave] = lsum; s_cnt[wave] = lcnt; }
    __syncthreads();
    if (threadIdx.x == 0) {
        part_sum[blockIdx.x] = s_sum[0] + s_sum[1] + s_sum[2] + s_sum[3];
        part_cnt[blockIdx.x] = s_cnt[0] + s_cnt[1] + s_cnt[2] + s_cnt[3];
    }
}

__global__ __launch_bounds__(BLOCK) void bce_finalize_kernel(
    const float* __restrict__ part_sum,
    const unsigned int* __restrict__ part_cnt,
    float* __restrict__ out)
{
    float        lsum = 0.0f;
    unsigned int lcnt = 0u;
    for (int i = threadIdx.x; i < GRID_BLOCKS; i += BLOCK) {
        lsum += part_sum[i];
        lcnt += part_cnt[i];
    }
    #pragma unroll
    for (int off = 32; off > 0; off >>= 1) {
        lsum += __shfl_down(lsum, off, 64);
        lcnt += __shfl_down(lcnt, off, 64);
    }
    __shared__ float        s_sum[4];
    __shared__ unsigned int s_cnt[4];
    const int lane = threadIdx.x & 63;
    const int wave = threadIdx.x >> 6;
    if (lane == 0) { s_sum[wave] = lsum; s_cnt[wave] = lcnt; }
    __syncthreads();
    if (threadIdx.x == 0) {
        float        bsum = s_sum[0] + s_sum[1] + s_sum[2] + s_sum[3];
        unsigned int bcnt = s_cnt[0] + s_cnt[1] + s_cnt[2] + s_cnt[3];
        out[0] = bsum / (float)bcnt;
    }
}

extern "C" void kernel_launch(void* const* d_in, const int* in_sizes, int n_in,
                              void* d_out, int out_size, void* d_ws, size_t ws_size,
                              hipStream_t stream) {
    const float* prob = (const float*)d_in[0];
    const int*   tgt  = (const int*)d_in[1];
    float*       out  = (float*)d_out;

    const int n = in_sizes[0];

    float*        part_sum = (float*)d_ws;
    unsigned int* part_cnt = (unsigned int*)((char*)d_ws + GRID_BLOCKS * sizeof(float));

    bce_reduce_kernel<<<GRID_BLOCKS, BLOCK, 0, stream>>>(prob, tgt, part_sum, part_cnt, n);
    bce_finalize_kernel<<<1, BLOCK, 0, stream>>>(part_sum, part_cnt, out);
}

// Round 4
// 330.356 us; speedup vs baseline: 1.0004x; 1.0004x over previous
//
#include <hip/hip_runtime.h>
#include <stdint.h>

// Masked BCE: cost = sum(t==1 ? -log(p) : t==0 ? -log(1-p) : 0) / count(t<=1)
//
// R4: wave-private double-buffered global_load_lds streaming.
// The global_load->VGPR path clamps at ~4.6 B/cyc/CU regardless of MLP or
// data residency (R2/R3 evidence); the direct-to-LDS DMA path demonstrated
// ~54 B/cyc/CU (m97). Each wave DMAs its own 1KB+1KB chunk pair into private
// LDS buffers, waits fine-grained vmcnt(2) (no __syncthreads in the loop),
// reads back with ds_read_b128, accumulates.

#define GRID_BLOCKS 2048
#define BLOCK 256
#define WAVES_PER_BLOCK 4
#define CHUNK_ELEMS 256   // per wave per chunk: 64 lanes x 4 elems (1 KB)

// s_waitcnt imm (gfx9 encoding): vmcnt[3:0] | expcnt<<4 | lgkmcnt<<8 | vmcnt[5:4]<<14
// expcnt=7, lgkmcnt=15 -> don't wait on those.
#define WAITCNT_VM(N) (((N) & 0xF) | (0x7 << 4) | (0xF << 8) | ((((N) >> 4) & 0x3) << 14))

typedef __attribute__((address_space(3))) void       lds_void_t;
typedef const __attribute__((address_space(1))) void gbl_void_t;

__global__ __launch_bounds__(BLOCK) void bce_reduce_kernel(
    const float* __restrict__ prob,
    const int* __restrict__ tgt,
    float* __restrict__ part_sum,        // [GRID_BLOCKS]
    unsigned int* __restrict__ part_cnt, // [GRID_BLOCKS]
    int nchunk,                          // n / CHUNK_ELEMS
    int n)
{
    // wave-private double buffers: [wave][buf] -> 1 KB prob + 1 KB tgt
    __shared__ float lds_p[WAVES_PER_BLOCK][2][CHUNK_ELEMS];
    __shared__ int   lds_t[WAVES_PER_BLOCK][2][CHUNK_ELEMS];

    const int lane = threadIdx.x & 63;
    const int wave = threadIdx.x >> 6;
    const int wgid = blockIdx.x * WAVES_PER_BLOCK + wave;  // global wave id
    const int W    = GRID_BLOCKS * WAVES_PER_BLOCK;        // total waves

    float        lsum = 0.0f;
    unsigned int lcnt = 0u;

    #define ACC(P, T)                                   \
    {                                                   \
        float v = ((T) == 1) ? (P) : 1.0f - (P);        \
        bool  c = (unsigned)(T) <= 1u;                  \
        float l = -__logf(v);                           \
        lsum += c ? l : 0.0f;                           \
        lcnt += c ? 1u : 0u;                            \
    }
    #define ACC4(P, T) ACC((P).x,(T).x) ACC((P).y,(T).y) ACC((P).z,(T).z) ACC((P).w,(T).w)

    // stage chunk `c` of array into wave-private buffer `b`.
    // DMA semantics: LDS dest = wave-uniform base + lane*16 (m104/m108),
    // global src per lane = base + lane*16 -> contiguous 1 KB.
    #define STAGE(c, b)                                                        \
    {                                                                          \
        __builtin_amdgcn_global_load_lds(                                      \
            (gbl_void_t*)(prob + (size_t)(c) * CHUNK_ELEMS + lane * 4),        \
            (lds_void_t*)&lds_p[wave][(b)][0], 16, 0, 0);                      \
        __builtin_amdgcn_global_load_lds(                                      \
            (gbl_void_t*)(tgt  + (size_t)(c) * CHUNK_ELEMS + lane * 4),        \
            (lds_void_t*)&lds_t[wave][(b)][0], 16, 0, 0);                      \
    }

    int c   = wgid;
    int buf = 0;
    if (c < nchunk) {
        STAGE(c, 0)   // prologue: fill buffer 0
    }
    while (c < nchunk) {
        const int cn = c + W;
        if (cn < nchunk) {
            STAGE(cn, buf ^ 1)                            // prefetch next chunk
            __builtin_amdgcn_s_waitcnt(WAITCNT_VM(2));    // current buf's 2 DMAs done
        } else {
            __builtin_amdgcn_s_waitcnt(WAITCNT_VM(0));    // drain (last iteration)
        }
        const float4 p = *(const float4*)&lds_p[wave][buf][lane * 4];
        const int4   t = *(const int4*)&lds_t[wave][buf][lane * 4];
        ACC4(p, t)
        buf ^= 1;
        c = cn;
    }

    // generic tail: elements [nchunk*CHUNK_ELEMS, n) via plain loads
    {
        const int gtid = blockIdx.x * BLOCK + threadIdx.x;
        for (int k = nchunk * CHUNK_ELEMS + gtid; k < n; k += GRID_BLOCKS * BLOCK) {
            float p = prob[k];
            int   t = tgt[k];
            ACC(p, t)
        }
    }

    // wave-64 reduction
    #pragma unroll
    for (int off = 32; off > 0; off >>= 1) {
        lsum += __shfl_down(lsum, off, 64);
        lcnt += __shfl_down(lcnt, off, 64);
    }

    // cross-wave via LDS (4 waves) — all wave DMAs drained above
    __shared__ float        s_sum[WAVES_PER_BLOCK];
    __shared__ unsigned int s_cnt[WAVES_PER_BLOCK];
    if (lane == 0) { s_sum[wave] = lsum; s_cnt[wave] = lcnt; }
    __syncthreads();
    if (threadIdx.x == 0) {
        part_sum[blockIdx.x] = s_sum[0] + s_sum[1] + s_sum[2] + s_sum[3];
        part_cnt[blockIdx.x] = s_cnt[0] + s_cnt[1] + s_cnt[2] + s_cnt[3];
    }
}

__global__ __launch_bounds__(BLOCK) void bce_finalize_kernel(
    const float* __restrict__ part_sum,
    const unsigned int* __restrict__ part_cnt,
    float* __restrict__ out)
{
    float        lsum = 0.0f;
    unsigned int lcnt = 0u;
    for (int i = threadIdx.x; i < GRID_BLOCKS; i += BLOCK) {
        lsum += part_sum[i];
        lcnt += part_cnt[i];
    }
    #pragma unroll
    for (int off = 32; off > 0; off >>= 1) {
        lsum += __shfl_down(lsum, off, 64);
        lcnt += __shfl_down(lcnt, off, 64);
    }
    __shared__ float        s_sum[4];
    __shared__ unsigned int s_cnt[4];
    const int lane = threadIdx.x & 63;
    const int wave = threadIdx.x >> 6;
    if (lane == 0) { s_sum[wave] = lsum; s_cnt[wave] = lcnt; }
    __syncthreads();
    if (threadIdx.x == 0) {
        float        bsum = s_sum[0] + s_sum[1] + s_sum[2] + s_sum[3];
        unsigned int bcnt = s_cnt[0] + s_cnt[1] + s_cnt[2] + s_cnt[3];
        out[0] = bsum / (float)bcnt;
    }
}

extern "C" void kernel_launch(void* const* d_in, const int* in_sizes, int n_in,
                              void* d_out, int out_size, void* d_ws, size_t ws_size,
                              hipStream_t stream) {
    const float* prob = (const float*)d_in[0];
    const int*   tgt  = (const int*)d_in[1];
    float*       out  = (float*)d_out;

    const int n      = in_sizes[0];
    const int nchunk = n / CHUNK_ELEMS;

    float*        part_sum = (float*)d_ws;
    unsigned int* part_cnt = (unsigned int*)((char*)d_ws + GRID_BLOCKS * sizeof(float));

    bce_reduce_kernel<<<GRID_BLOCKS, BLOCK, 0, stream>>>(prob, tgt, part_sum, part_cnt, nchunk, n);
    bce_finalize_kernel<<<1, BLOCK, 0, stream>>>(part_sum, part_cnt, out);
}